// Round 2
// baseline (146.882 us; speedup 1.0000x reference)
//
#include <hip/hip_runtime.h>
#include <hip/hip_bf16.h>

// ODEFunc: out[i] = x_N(x_i) + sum_j A[i,j] * ( edgeMLP(x_i, x_j) + wA0*x_i + wA1*x_j )
//
// R14 = R13 + residency attack (tail-phase diagnosis):
//   R13 showed: 20% VALU cut -> dur unchanged. Not issue-bound. 36 arch VGPR +
//   32 MFMA C/D regs ~= 68-72 unified -> 7 waves/EU -> 7 blocks/CU capacity,
//   but grid = 2048 blocks = 8 blocks/CU of work -> 256-block straggler tail at
//   ~12% occupancy explains avg occupancy 45% and the flat dur.
//   * register diet to <=64 unified -> 8 waves/EU, ALL 2048 blocks co-resident:
//     - drop x prefetch reg (x slice is 8KB/wave, shared across row-waves,
//       L1/L2-hot after iter 0; load at use)
//     - single 32-bit float4-index `o` for BOTH x and A (row/jbase are
//       wave-uniform -> SGPR bases), no per-lane 64-bit pointers
//   * __launch_bounds__(256, 8)
//   * numerics identical to R13 (passed, absmax 7.8e-3)
//
// MFMA layout (32x32x16, validated R2-R11):
//   A[m][k]: m = lane&31, k = (lane>>5)*8 + e
//   B[k][n]: n = lane&31, k = (lane>>5)*8 + e
//   D[m][n]: n = lane&31, m = (reg&3) + 8*(reg>>2) + 4*(lane>>5)
// Only m<16 carries WA1; D regs 8..15 ignored. C = 0 (bA1 applied in epilogue).
// In-lane epilogue: A_ij distributes into the WA2 dot; skip term in half 0 only.

#define NN 4096

typedef __fp16 half8  __attribute__((ext_vector_type(8)));
typedef __fp16 half2v __attribute__((ext_vector_type(2)));
typedef __attribute__((ext_vector_type(4)))  float f32x4;
typedef __attribute__((ext_vector_type(16))) float f32x16;

__device__ __forceinline__ half2v cvt2(float lo, float hi) {
    return __builtin_amdgcn_cvt_pkrtz(lo, hi);
}

__global__ __launch_bounds__(256, 8) void odef_kernel(
    const float* __restrict__ x,  const float* __restrict__ A,
    const float* __restrict__ WA0, const float* __restrict__ bA0,
    const float* __restrict__ WA1, const float* __restrict__ bA1,
    const float* __restrict__ WA2, const float* __restrict__ bA2,
    const float* __restrict__ Wm0, const float* __restrict__ bm0,
    const float* __restrict__ Wm1, const float* __restrict__ bm1,
    const float* __restrict__ wA,  const float* __restrict__ wf,
    float* __restrict__ out)
{
    __shared__ float partial[4];

    const int tid  = threadIdx.x;
    const int wave = tid >> 6;
    const int lane = tid & 63;
    const int n    = lane & 31;      // MFMA col (B n / D n / A m)
    const int half = lane >> 5;      // k-half (A/B), row-half (D)
    const int row  = blockIdx.x * 2 + (wave >> 1);   // 2 rows per block
    const int jbase = (wave & 1) * (NN / 2);         // 2 waves split the j range

    const float xi = x[row];

    // ---- A-fragment: WA1[m][k] in f16; m = n (<16), k = half*8 + e; rows >=16 zero
    union { half2v h2[4]; half8 h8; } au;
    #pragma unroll
    for (int p = 0; p < 4; ++p) {
        float lo = 0.f, hi = 0.f;
        if (n < 16) {
            int k = half * 8 + p * 2;
            lo = WA1[n * 16 + k];
            hi = WA1[n * 16 + k + 1];
        }
        au.h2[p] = cvt2(lo, hi);
    }

    // ---- h0 constants, packed f16: u_k(i) = WA0[k,0]*xi + bA0[k]; w1_k = WA0[k,1]
    half2v u2h[4], w2h[4];
    #pragma unroll
    for (int p = 0; p < 4; ++p) {
        int k0 = half * 8 + p * 2;
        u2h[p] = cvt2(fmaf(WA0[2 * k0],     xi, bA0[k0]),
                      fmaf(WA0[2 * k0 + 2], xi, bA0[k0 + 1]));
        w2h[p] = cvt2(WA0[2 * k0 + 1], WA0[2 * k0 + 3]);
    }

    // ---- layer-2 weights + bA1 as packed-f16 pairs matching D regs (2p, 2p+1)
    //      m(r) = (r&3) + 8*(r>>2) + 4*half ; pairs are consecutive in m
    half2v wa2h[4], bb[4];
    #pragma unroll
    for (int p = 0; p < 4; ++p) {
        int r  = 2 * p;
        int m0 = (r & 3) + 8 * (r >> 2) + 4 * half;
        wa2h[p] = cvt2(WA2[m0], WA2[m0 + 1]);
        bb[p]   = cvt2(bA1[m0], bA1[m0 + 1]);
    }

    // skip term: only half 0 adds it (each j is held by both halves)
    const float wA1h = half ? 0.f : wA[1];
    const float c0h  = half ? 0.f : (bA2[0] + wA[0] * xi);
    const half2v z2 = { (__fp16)0.f, (__fp16)0.f };
    const f32x16 zc = {};   // zero C-operand -> folds to MFMA inline constant 0

    // Wave-uniform SGPR bases; one 32-bit float4 index per lane serves both
    // streams: j = jbase + it*128 + 4n + q  ->  float4 index o = n + it*32.
    const f32x4* __restrict__ xb = (const f32x4*)(x + jbase);
    const f32x4* __restrict__ ab = (const f32x4*)(A + (size_t)row * NN + jbase);

    float acc0 = 0.f, acc1 = 0.f;

    // one 128-j macro group: 4 MFMA groups, 2-deep MFMA pipeline (proven R10/R11)
    auto body = [&](const f32x4 xv, const f32x4 av) {
        #pragma unroll
        for (int q = 0; q < 4; q += 2) {
            // build + MFMA for group q (native v2f16 -> v_pk_fma/max_f16)
            half2v xg0 = cvt2(xv[q], xv[q]);
            union { half2v h2[4]; half8 h8; } b0;
            #pragma unroll
            for (int p = 0; p < 4; ++p)
                b0.h2[p] = __builtin_elementwise_max(w2h[p] * xg0 + u2h[p], z2);
            f32x16 d0 = __builtin_amdgcn_mfma_f32_32x32x16_f16(au.h8, b0.h8, zc, 0, 0, 0);

            // build + MFMA for group q+1 (covers MFMA0 + D-read latency)
            half2v xg1 = cvt2(xv[q + 1], xv[q + 1]);
            union { half2v h2[4]; half8 h8; } b1;
            #pragma unroll
            for (int p = 0; p < 4; ++p)
                b1.h2[p] = __builtin_elementwise_max(w2h[p] * xg1 + u2h[p], z2);
            f32x16 d1 = __builtin_amdgcn_mfma_f32_32x32x16_f16(au.h8, b1.h8, zc, 0, 0, 0);

            // epilogue q: packed-f16, D regs 0..7 (rows < 16)
            {
                float pp = fmaf(wA1h, xv[q], c0h);
                #pragma unroll
                for (int p = 0; p < 4; ++p) {
                    half2v t = __builtin_elementwise_max(
                        cvt2(d0[2 * p], d0[2 * p + 1]) + bb[p], z2);
                    pp = __builtin_amdgcn_fdot2(t, wa2h[p], pp, false);
                }
                acc0 = fmaf(av[q], pp, acc0);
            }
            // epilogue q+1
            {
                float pp = fmaf(wA1h, xv[q + 1], c0h);
                #pragma unroll
                for (int p = 0; p < 4; ++p) {
                    half2v t = __builtin_elementwise_max(
                        cvt2(d1[2 * p], d1[2 * p + 1]) + bb[p], z2);
                    pp = __builtin_amdgcn_fdot2(t, wa2h[p], pp, false);
                }
                acc1 = fmaf(av[q + 1], pp, acc1);
            }
        }
    };

    // ---- 15 hot macro-iters (A prefetched 1 macro ahead; x loaded at use,
    //      L1/L2-hot since every row-wave reads the same 8KB slice), peeled tail
    int o = n;
    f32x4 ac = ab[o];
    for (int it = 0; it < 15; ++it) {
        f32x4 aN = ab[o + 32];       // 32 float4 = 128 floats ahead
        f32x4 xv = xb[o];
        body(xv, ac);
        ac = aN;
        o += 32;
    }
    {
        f32x4 xv = xb[o];
        body(xv, ac);
    }

    // ---- reduce wave, then combine the two j-half waves per row
    float acc = acc0 + acc1;
    #pragma unroll
    for (int off = 32; off > 0; off >>= 1)
        acc += __shfl_xor(acc, off);
    if (lane == 0) partial[wave] = acc;
    __syncthreads();

    if (lane == 0 && (wave & 1) == 0) {
        // node MLP (fp32 exact): x_N = relu(x*Wm0+bm0)@Wm1 + bm1 + wf*x
        float xn = fmaf(wf[0], xi, bm1[0]);
        #pragma unroll
        for (int h = 0; h < 16; ++h)
            xn = fmaf(Wm1[h], fmaxf(fmaf(Wm0[h], xi, bm0[h]), 0.f), xn);
        out[row] = xn + partial[wave] + partial[wave + 1];
    }
}

extern "C" void kernel_launch(void* const* d_in, const int* in_sizes, int n_in,
                              void* d_out, int out_size, void* d_ws, size_t ws_size,
                              hipStream_t stream) {
    const float* x   = (const float*)d_in[1];
    const float* A   = (const float*)d_in[2];
    const float* WA0 = (const float*)d_in[3];
    const float* bA0 = (const float*)d_in[4];
    const float* WA1 = (const float*)d_in[5];
    const float* bA1 = (const float*)d_in[6];
    const float* WA2 = (const float*)d_in[7];
    const float* bA2 = (const float*)d_in[8];
    const float* Wm0 = (const float*)d_in[9];
    const float* bm0 = (const float*)d_in[10];
    const float* Wm1 = (const float*)d_in[11];
    const float* bm1 = (const float*)d_in[12];
    const float* wA  = (const float*)d_in[13];
    const float* wf  = (const float*)d_in[14];
    float* out = (float*)d_out;

    odef_kernel<<<NN / 2, 256, 0, stream>>>(x, A, WA0, bA0, WA1, bA1, WA2, bA2,
                                            Wm0, bm0, Wm1, bm1, wA, wf, out);
}

// Round 3
// 146.822 us; speedup vs baseline: 1.0004x; 1.0004x over previous
//
#include <hip/hip_runtime.h>
#include <hip/hip_bf16.h>

// ODEFunc: out[i] = x_N(x_i) + sum_j A[i,j] * ( edgeMLP(x_i, x_j) + wA0*x_i + wA1*x_j )
//
// R15 = R14 + row-rotated j-walk (channel-camping diagnosis):
//   R13 (-20% VALU) and R14 (+10pt occupancy) both left dur at ~48-50us.
//   Effective A-stream throughput is pinned at ~1.3 TB/s (21% of float4-copy
//   ceiling) despite ~4MB in flight chip-wide. Address audit: in lockstep all
//   8192 row-waves read A at row*16KB + jsel*8KB + it*512 + lane*16 -- the
//   concurrent stream differs only in a 512-B low-order window -> HBM
//   channel/bank camping -> queue-inflated latency (~3us implied).
//   * Each wave starts its j-walk at macro-iter (row & 15) and wraps (row sum
//     is permutation-invariant). Concurrent addresses now spread over the full
//     16KB row stride (16 phases x 512B x 2 j-halves) -> all channels hit.
//   * Everything else byte-identical to R14 (proven MFMA structure, packed
//     epilogue, C=0, 32-reg diet, (256,8)).
//
// MFMA layout (32x32x16, validated R2-R11):
//   A[m][k]: m = lane&31, k = (lane>>5)*8 + e
//   B[k][n]: n = lane&31, k = (lane>>5)*8 + e
//   D[m][n]: n = lane&31, m = (reg&3) + 8*(reg>>2) + 4*(lane>>5)
// Only m<16 carries WA1; D regs 8..15 ignored. C = 0 (bA1 applied in epilogue).
// In-lane epilogue: A_ij distributes into the WA2 dot; skip term in half 0 only.

#define NN 4096

typedef __fp16 half8  __attribute__((ext_vector_type(8)));
typedef __fp16 half2v __attribute__((ext_vector_type(2)));
typedef __attribute__((ext_vector_type(4)))  float f32x4;
typedef __attribute__((ext_vector_type(16))) float f32x16;

__device__ __forceinline__ half2v cvt2(float lo, float hi) {
    return __builtin_amdgcn_cvt_pkrtz(lo, hi);
}

__global__ __launch_bounds__(256, 8) void odef_kernel(
    const float* __restrict__ x,  const float* __restrict__ A,
    const float* __restrict__ WA0, const float* __restrict__ bA0,
    const float* __restrict__ WA1, const float* __restrict__ bA1,
    const float* __restrict__ WA2, const float* __restrict__ bA2,
    const float* __restrict__ Wm0, const float* __restrict__ bm0,
    const float* __restrict__ Wm1, const float* __restrict__ bm1,
    const float* __restrict__ wA,  const float* __restrict__ wf,
    float* __restrict__ out)
{
    __shared__ float partial[4];

    const int tid  = threadIdx.x;
    const int wave = tid >> 6;
    const int lane = tid & 63;
    const int n    = lane & 31;      // MFMA col (B n / D n / A m)
    const int half = lane >> 5;      // k-half (A/B), row-half (D)
    const int row  = blockIdx.x * 2 + (wave >> 1);   // 2 rows per block
    const int jbase = (wave & 1) * (NN / 2);         // 2 waves split the j range

    const float xi = x[row];

    // ---- A-fragment: WA1[m][k] in f16; m = n (<16), k = half*8 + e; rows >=16 zero
    union { half2v h2[4]; half8 h8; } au;
    #pragma unroll
    for (int p = 0; p < 4; ++p) {
        float lo = 0.f, hi = 0.f;
        if (n < 16) {
            int k = half * 8 + p * 2;
            lo = WA1[n * 16 + k];
            hi = WA1[n * 16 + k + 1];
        }
        au.h2[p] = cvt2(lo, hi);
    }

    // ---- h0 constants, packed f16: u_k(i) = WA0[k,0]*xi + bA0[k]; w1_k = WA0[k,1]
    half2v u2h[4], w2h[4];
    #pragma unroll
    for (int p = 0; p < 4; ++p) {
        int k0 = half * 8 + p * 2;
        u2h[p] = cvt2(fmaf(WA0[2 * k0],     xi, bA0[k0]),
                      fmaf(WA0[2 * k0 + 2], xi, bA0[k0 + 1]));
        w2h[p] = cvt2(WA0[2 * k0 + 1], WA0[2 * k0 + 3]);
    }

    // ---- layer-2 weights + bA1 as packed-f16 pairs matching D regs (2p, 2p+1)
    //      m(r) = (r&3) + 8*(r>>2) + 4*half ; pairs are consecutive in m
    half2v wa2h[4], bb[4];
    #pragma unroll
    for (int p = 0; p < 4; ++p) {
        int r  = 2 * p;
        int m0 = (r & 3) + 8 * (r >> 2) + 4 * half;
        wa2h[p] = cvt2(WA2[m0], WA2[m0 + 1]);
        bb[p]   = cvt2(bA1[m0], bA1[m0 + 1]);
    }

    // skip term: only half 0 adds it (each j is held by both halves)
    const float wA1h = half ? 0.f : wA[1];
    const float c0h  = half ? 0.f : (bA2[0] + wA[0] * xi);
    const half2v z2 = { (__fp16)0.f, (__fp16)0.f };
    const f32x16 zc = {};   // zero C-operand -> folds to MFMA inline constant 0

    // Wave-uniform SGPR bases; one 32-bit float4 index per lane serves both
    // streams: j = jbase + it*128 + 4n + q  ->  float4 index o = n + it*32.
    const f32x4* __restrict__ xb = (const f32x4*)(x + jbase);
    const f32x4* __restrict__ ab = (const f32x4*)(A + (size_t)row * NN + jbase);

    float acc0 = 0.f, acc1 = 0.f;

    // one 128-j macro group: 4 MFMA groups, 2-deep MFMA pipeline (proven R10/R11)
    auto body = [&](const f32x4 xv, const f32x4 av) {
        #pragma unroll
        for (int q = 0; q < 4; q += 2) {
            // build + MFMA for group q (native v2f16 -> v_pk_fma/max_f16)
            half2v xg0 = cvt2(xv[q], xv[q]);
            union { half2v h2[4]; half8 h8; } b0;
            #pragma unroll
            for (int p = 0; p < 4; ++p)
                b0.h2[p] = __builtin_elementwise_max(w2h[p] * xg0 + u2h[p], z2);
            f32x16 d0 = __builtin_amdgcn_mfma_f32_32x32x16_f16(au.h8, b0.h8, zc, 0, 0, 0);

            // build + MFMA for group q+1 (covers MFMA0 + D-read latency)
            half2v xg1 = cvt2(xv[q + 1], xv[q + 1]);
            union { half2v h2[4]; half8 h8; } b1;
            #pragma unroll
            for (int p = 0; p < 4; ++p)
                b1.h2[p] = __builtin_elementwise_max(w2h[p] * xg1 + u2h[p], z2);
            f32x16 d1 = __builtin_amdgcn_mfma_f32_32x32x16_f16(au.h8, b1.h8, zc, 0, 0, 0);

            // epilogue q: packed-f16, D regs 0..7 (rows < 16)
            {
                float pp = fmaf(wA1h, xv[q], c0h);
                #pragma unroll
                for (int p = 0; p < 4; ++p) {
                    half2v t = __builtin_elementwise_max(
                        cvt2(d0[2 * p], d0[2 * p + 1]) + bb[p], z2);
                    pp = __builtin_amdgcn_fdot2(t, wa2h[p], pp, false);
                }
                acc0 = fmaf(av[q], pp, acc0);
            }
            // epilogue q+1
            {
                float pp = fmaf(wA1h, xv[q + 1], c0h);
                #pragma unroll
                for (int p = 0; p < 4; ++p) {
                    half2v t = __builtin_elementwise_max(
                        cvt2(d1[2 * p], d1[2 * p + 1]) + bb[p], z2);
                    pp = __builtin_amdgcn_fdot2(t, wa2h[p], pp, false);
                }
                acc1 = fmaf(av[q + 1], pp, acc1);
            }
        }
    };

    // ---- 16 macro-iters, walk rotated by (row & 15) with wraparound so
    //      concurrent waves touch de-phased addresses (channel spread).
    //      Range: 512 float4 per j-half; stride 32 float4 per macro-iter.
    int o = n + (row & 15) * 32;
    f32x4 ac = ab[o];
    for (int it = 0; it < 15; ++it) {
        int ow = o + 32;
        if (ow >= 512) ow -= 512;
        f32x4 aN = ab[ow];           // prefetch next macro (wrapped)
        f32x4 xv = xb[o];            // x slice is L1/L2-hot (shared by all rows)
        body(xv, ac);
        ac = aN;
        o = ow;
    }
    {
        f32x4 xv = xb[o];
        body(xv, ac);
    }

    // ---- reduce wave, then combine the two j-half waves per row
    float acc = acc0 + acc1;
    #pragma unroll
    for (int off = 32; off > 0; off >>= 1)
        acc += __shfl_xor(acc, off);
    if (lane == 0) partial[wave] = acc;
    __syncthreads();

    if (lane == 0 && (wave & 1) == 0) {
        // node MLP (fp32 exact): x_N = relu(x*Wm0+bm0)@Wm1 + bm1 + wf*x
        float xn = fmaf(wf[0], xi, bm1[0]);
        #pragma unroll
        for (int h = 0; h < 16; ++h)
            xn = fmaf(Wm1[h], fmaxf(fmaf(Wm0[h], xi, bm0[h]), 0.f), xn);
        out[row] = xn + partial[wave] + partial[wave + 1];
    }
}

extern "C" void kernel_launch(void* const* d_in, const int* in_sizes, int n_in,
                              void* d_out, int out_size, void* d_ws, size_t ws_size,
                              hipStream_t stream) {
    const float* x   = (const float*)d_in[1];
    const float* A   = (const float*)d_in[2];
    const float* WA0 = (const float*)d_in[3];
    const float* bA0 = (const float*)d_in[4];
    const float* WA1 = (const float*)d_in[5];
    const float* bA1 = (const float*)d_in[6];
    const float* WA2 = (const float*)d_in[7];
    const float* bA2 = (const float*)d_in[8];
    const float* Wm0 = (const float*)d_in[9];
    const float* bm0 = (const float*)d_in[10];
    const float* Wm1 = (const float*)d_in[11];
    const float* bm1 = (const float*)d_in[12];
    const float* wA  = (const float*)d_in[13];
    const float* wf  = (const float*)d_in[14];
    float* out = (float*)d_out;

    odef_kernel<<<NN / 2, 256, 0, stream>>>(x, A, WA0, bA0, WA1, bA1, WA2, bA2,
                                            Wm0, bm0, Wm1, bm1, wA, wf, out);
}

// Round 4
// 143.799 us; speedup vs baseline: 1.0214x; 1.0210x over previous
//
#include <hip/hip_runtime.h>
#include <hip/hip_bf16.h>

// ODEFunc: out[i] = x_N(x_i) + sum_j A[i,j] * ( edgeMLP(x_i, x_j) + wA0*x_i + wA1*x_j )
//
// R16 = R15 + memory-pipeline restructure (latency-serialization diagnosis):
//   R12-R15 invariant at ~47us across VALU -20%, occupancy +15pt, address
//   de-phasing => stall-dominated. Arithmetic: 113K cyc wall / 16 macro-iters
//   = ~7000 cyc/iter vs ~500 cyc issue -> ~6500 cyc stall per iter per wave.
//   Cause: {A-prefetch, x-load} share the in-order vmcnt counter with depth 1;
//   waiting for the x-load drains the A-prefetch too -> effective depth ~0;
//   every iter pays full loaded latency, and latency scales with resident
//   waves (why R14's occupancy gain was null).
//   * x staged to LDS once per block (16KB); per-iter x becomes ds_read_b128
//     (lgkm path, off the vmem queue) -> A-loads are the ONLY vmem ops in the
//     loop -> compiler emits vmcnt(2)-style waits, 3 loads stay in flight.
//   * A prefetch depth 3: rotating a0..a3, statically renamed (no dyn idx).
//   * ds_read prefetched 1 iter ahead (xv/xn).
//   * __launch_bounds__(256,6): +16 prefetch VGPRs must not spill.
//   * Everything else identical to R15 (proven MFMA structure, packed f16
//     epilogue, C=0; numerics bit-identical, absmax expected 7.8e-3).
//
// MFMA layout (32x32x16, validated R2-R11):
//   A[m][k]: m = lane&31, k = (lane>>5)*8 + e
//   B[k][n]: n = lane&31, k = (lane>>5)*8 + e
//   D[m][n]: n = lane&31, m = (reg&3) + 8*(reg>>2) + 4*(lane>>5)
// Only m<16 carries WA1; D regs 8..15 ignored. C = 0 (bA1 applied in epilogue).
// In-lane epilogue: A_ij distributes into the WA2 dot; skip term in half 0 only.

#define NN 4096

typedef __fp16 half8  __attribute__((ext_vector_type(8)));
typedef __fp16 half2v __attribute__((ext_vector_type(2)));
typedef __attribute__((ext_vector_type(4)))  float f32x4;
typedef __attribute__((ext_vector_type(16))) float f32x16;

__device__ __forceinline__ half2v cvt2(float lo, float hi) {
    return __builtin_amdgcn_cvt_pkrtz(lo, hi);
}

__global__ __launch_bounds__(256, 6) void odef_kernel(
    const float* __restrict__ x,  const float* __restrict__ A,
    const float* __restrict__ WA0, const float* __restrict__ bA0,
    const float* __restrict__ WA1, const float* __restrict__ bA1,
    const float* __restrict__ WA2, const float* __restrict__ bA2,
    const float* __restrict__ Wm0, const float* __restrict__ bm0,
    const float* __restrict__ Wm1, const float* __restrict__ bm1,
    const float* __restrict__ wA,  const float* __restrict__ wf,
    float* __restrict__ out)
{
    __shared__ float xs[NN];         // full x vector, 16KB
    __shared__ float partial[4];

    const int tid  = threadIdx.x;
    const int wave = tid >> 6;
    const int lane = tid & 63;
    const int n    = lane & 31;      // MFMA col (B n / D n / A m)
    const int half = lane >> 5;      // k-half (A/B), row-half (D)
    const int row  = blockIdx.x * 2 + (wave >> 1);   // 2 rows per block
    const int jbase = (wave & 1) * (NN / 2);         // 2 waves split the j range

    // ---- cooperative x -> LDS (1024 float4, 4 per thread)
    {
        const f32x4* xsrc = (const f32x4*)x;
        f32x4* xdst = (f32x4*)xs;
        #pragma unroll
        for (int i = 0; i < 4; ++i)
            xdst[tid + 256 * i] = xsrc[tid + 256 * i];
    }

    const float xi = x[row];

    // ---- A-fragment: WA1[m][k] in f16; m = n (<16), k = half*8 + e; rows >=16 zero
    union { half2v h2[4]; half8 h8; } au;
    #pragma unroll
    for (int p = 0; p < 4; ++p) {
        float lo = 0.f, hi = 0.f;
        if (n < 16) {
            int k = half * 8 + p * 2;
            lo = WA1[n * 16 + k];
            hi = WA1[n * 16 + k + 1];
        }
        au.h2[p] = cvt2(lo, hi);
    }

    // ---- h0 constants, packed f16: u_k(i) = WA0[k,0]*xi + bA0[k]; w1_k = WA0[k,1]
    half2v u2h[4], w2h[4];
    #pragma unroll
    for (int p = 0; p < 4; ++p) {
        int k0 = half * 8 + p * 2;
        u2h[p] = cvt2(fmaf(WA0[2 * k0],     xi, bA0[k0]),
                      fmaf(WA0[2 * k0 + 2], xi, bA0[k0 + 1]));
        w2h[p] = cvt2(WA0[2 * k0 + 1], WA0[2 * k0 + 3]);
    }

    // ---- layer-2 weights + bA1 as packed-f16 pairs matching D regs (2p, 2p+1)
    half2v wa2h[4], bb[4];
    #pragma unroll
    for (int p = 0; p < 4; ++p) {
        int r  = 2 * p;
        int m0 = (r & 3) + 8 * (r >> 2) + 4 * half;
        wa2h[p] = cvt2(WA2[m0], WA2[m0 + 1]);
        bb[p]   = cvt2(bA1[m0], bA1[m0 + 1]);
    }

    // skip term: only half 0 adds it (each j is held by both halves)
    const float wA1h = half ? 0.f : wA[1];
    const float c0h  = half ? 0.f : (bA2[0] + wA[0] * xi);
    const half2v z2 = { (__fp16)0.f, (__fp16)0.f };
    const f32x16 zc = {};   // zero C-operand -> folds to MFMA inline constant 0

    // j = jbase + it*128 + 4n + q  ->  float4 index o = n + it*32
    const f32x4* __restrict__ ab  = (const f32x4*)(A + (size_t)row * NN + jbase);
    const f32x4* __restrict__ xls = (const f32x4*)(xs + jbase);

    float acc0 = 0.f, acc1 = 0.f;

    // one 128-j macro group: 4 MFMA groups, 2-deep MFMA pipeline (proven R10/R11)
    auto body = [&](const f32x4 xv, const f32x4 av) {
        #pragma unroll
        for (int q = 0; q < 4; q += 2) {
            half2v xg0 = cvt2(xv[q], xv[q]);
            union { half2v h2[4]; half8 h8; } b0;
            #pragma unroll
            for (int p = 0; p < 4; ++p)
                b0.h2[p] = __builtin_elementwise_max(w2h[p] * xg0 + u2h[p], z2);
            f32x16 d0 = __builtin_amdgcn_mfma_f32_32x32x16_f16(au.h8, b0.h8, zc, 0, 0, 0);

            half2v xg1 = cvt2(xv[q + 1], xv[q + 1]);
            union { half2v h2[4]; half8 h8; } b1;
            #pragma unroll
            for (int p = 0; p < 4; ++p)
                b1.h2[p] = __builtin_elementwise_max(w2h[p] * xg1 + u2h[p], z2);
            f32x16 d1 = __builtin_amdgcn_mfma_f32_32x32x16_f16(au.h8, b1.h8, zc, 0, 0, 0);

            // epilogue q: packed-f16, D regs 0..7 (rows < 16)
            {
                float pp = fmaf(wA1h, xv[q], c0h);
                #pragma unroll
                for (int p = 0; p < 4; ++p) {
                    half2v t = __builtin_elementwise_max(
                        cvt2(d0[2 * p], d0[2 * p + 1]) + bb[p], z2);
                    pp = __builtin_amdgcn_fdot2(t, wa2h[p], pp, false);
                }
                acc0 = fmaf(av[q], pp, acc0);
            }
            // epilogue q+1
            {
                float pp = fmaf(wA1h, xv[q + 1], c0h);
                #pragma unroll
                for (int p = 0; p < 4; ++p) {
                    half2v t = __builtin_elementwise_max(
                        cvt2(d1[2 * p], d1[2 * p + 1]) + bb[p], z2);
                    pp = __builtin_amdgcn_fdot2(t, wa2h[p], pp, false);
                }
                acc1 = fmaf(av[q + 1], pp, acc1);
            }
        }
    };

    __syncthreads();                 // xs ready

    // ---- 16 macro-iters; A-loads depth-3 in flight, x via LDS 1 ahead
    int o = n;
    f32x4 a0 = ab[o];
    f32x4 a1 = ab[o + 32];
    f32x4 a2 = ab[o + 64];
    f32x4 xv = xls[o];
    for (int it = 0; it < 16; ++it) {
        const int opref = o + ((it + 3 < 16) ? 96 : 0);   // clamped re-load, rotated away
        const int oxn   = o + ((it + 1 < 16) ? 32 : 0);
        f32x4 a3 = ab[opref];
        f32x4 xn = xls[oxn];
        body(xv, a0);
        a0 = a1; a1 = a2; a2 = a3; xv = xn;
        o += 32;
    }

    // ---- reduce wave, then combine the two j-half waves per row
    float acc = acc0 + acc1;
    #pragma unroll
    for (int off = 32; off > 0; off >>= 1)
        acc += __shfl_xor(acc, off);
    if (lane == 0) partial[wave] = acc;
    __syncthreads();

    if (lane == 0 && (wave & 1) == 0) {
        // node MLP (fp32 exact): x_N = relu(x*Wm0+bm0)@Wm1 + bm1 + wf*x
        float xn = fmaf(wf[0], xi, bm1[0]);
        #pragma unroll
        for (int h = 0; h < 16; ++h)
            xn = fmaf(Wm1[h], fmaxf(fmaf(Wm0[h], xi, bm0[h]), 0.f), xn);
        out[row] = xn + partial[wave] + partial[wave + 1];
    }
}

extern "C" void kernel_launch(void* const* d_in, const int* in_sizes, int n_in,
                              void* d_out, int out_size, void* d_ws, size_t ws_size,
                              hipStream_t stream) {
    const float* x   = (const float*)d_in[1];
    const float* A   = (const float*)d_in[2];
    const float* WA0 = (const float*)d_in[3];
    const float* bA0 = (const float*)d_in[4];
    const float* WA1 = (const float*)d_in[5];
    const float* bA1 = (const float*)d_in[6];
    const float* WA2 = (const float*)d_in[7];
    const float* bA2 = (const float*)d_in[8];
    const float* Wm0 = (const float*)d_in[9];
    const float* bm0 = (const float*)d_in[10];
    const float* Wm1 = (const float*)d_in[11];
    const float* bm1 = (const float*)d_in[12];
    const float* wA  = (const float*)d_in[13];
    const float* wf  = (const float*)d_in[14];
    float* out = (float*)d_out;

    odef_kernel<<<NN / 2, 256, 0, stream>>>(x, A, WA0, bA0, WA1, bA1, WA2, bA2,
                                            Wm0, bm0, Wm1, bm1, wA, wf, out);
}

// Round 5
// 142.653 us; speedup vs baseline: 1.0296x; 1.0080x over previous
//
#include <hip/hip_runtime.h>
#include <hip/hip_bf16.h>

// ODEFunc: out[i] = x_N(x_i) + sum_j A[i,j] * ( edgeMLP(x_i, x_j) + wA0*x_i + wA1*x_j )
//
// R17 = hand-controlled DMA pipeline (compiler-defeats-prefetch diagnosis):
//   R13-R16: four structural nulls (VALU -20%, occupancy +15pt, de-phasing,
//   reg-prefetch depth 3 + x->LDS) with wall pinned at ~46us. Machine balance
//   says ~11-13us (issue ~3-4K cyc/wave, mem floor 64MB@6.3TB/s = 10.2us).
//   Only surviving mechanism: compiler collapses source-level prefetch to
//   effective vmcnt(0)/iter (the documented m97-structure failure mode) ->
//   every 512B macro-iter pays full queue-inflated latency (~6-7K cyc).
//   * A staged via __builtin_amdgcn_global_load_lds (async DMA, no dest regs)
//     into a per-wave 4-slot x 1KB LDS ring; paced by hand-written counted
//     s_waitcnt vmcnt(3)/(2)/(1)/(0) inline asm. DMAs are the ONLY vmem ops
//     in the loop -> counts exact. Never drains mid-loop (T3/T4 pattern).
//   * 1 wave = 1 full row (16 DMA pairs x 1KB = 256 floats each); 4 rows per
//     256-thread block; grid 1024 = exactly 4 blocks/CU (no straggler tail);
//     LDS 16KB xs + 16KB ring = 32KB -> 4 blocks resident.
//   * Ring safety by construction: issue(P+3) writes slot (P-1)&3, whose
//     ds_reads were consumed by iter P-1's body (register use => retired).
//   * Body/numerics identical to R13-R16 (MFMA layout, packed-f16 epilogue,
//     C=0). Row now summed by one wave (order change; absmax may shift).
//
// MFMA layout (32x32x16, validated R2-R11):
//   A[m][k]: m = lane&31, k = (lane>>5)*8 + e
//   B[k][n]: n = lane&31, k = (lane>>5)*8 + e
//   D[m][n]: n = lane&31, m = (reg&3) + 8*(reg>>2) + 4*(lane>>5)
// Only m<16 carries WA1; D regs 8..15 ignored. C = 0 (bA1 applied in epilogue).
// In-lane epilogue: A_ij distributes into the WA2 dot; skip term in half 0 only.

#define NN 4096

typedef __fp16 half8  __attribute__((ext_vector_type(8)));
typedef __fp16 half2v __attribute__((ext_vector_type(2)));
typedef __attribute__((ext_vector_type(4)))  float f32x4;
typedef __attribute__((ext_vector_type(16))) float f32x16;

__device__ __forceinline__ half2v cvt2(float lo, float hi) {
    return __builtin_amdgcn_cvt_pkrtz(lo, hi);
}

__global__ __launch_bounds__(256, 4) void odef_kernel(
    const float* __restrict__ x,  const float* __restrict__ A,
    const float* __restrict__ WA0, const float* __restrict__ bA0,
    const float* __restrict__ WA1, const float* __restrict__ bA1,
    const float* __restrict__ WA2, const float* __restrict__ bA2,
    const float* __restrict__ Wm0, const float* __restrict__ bm0,
    const float* __restrict__ Wm1, const float* __restrict__ bm1,
    const float* __restrict__ wA,  const float* __restrict__ wf,
    float* __restrict__ out)
{
    __shared__ float xs[NN];              // full x vector, 16KB
    __shared__ float ring[4][4][256];     // [wave][slot][1KB]: per-wave DMA ring, 16KB

    const int tid  = threadIdx.x;
    const int wave = tid >> 6;
    const int lane = tid & 63;
    const int n    = lane & 31;      // MFMA col (B n / D n / A m)
    const int half = lane >> 5;      // k-half (A/B), row-half (D)
    const int row  = blockIdx.x * 4 + wave;          // 1 full row per wave

    // ---- cooperative x -> LDS (1024 float4, 4 per thread)
    {
        const f32x4* xsrc = (const f32x4*)x;
        f32x4* xdst = (f32x4*)xs;
        #pragma unroll
        for (int i = 0; i < 4; ++i)
            xdst[tid + 256 * i] = xsrc[tid + 256 * i];
    }

    const float xi = x[row];
    const float* arow = A + (size_t)row * NN;

    // DMA: stage pair p (256 floats = groups 2p, 2p+1) into slot p&3.
    // LDS dest is wave-uniform base; HW writes base + lane*16 (linear 1KB).
    // Global src is per-lane: lane l covers float4 index p*64 + l.
    auto issue = [&](int pair) {
        const float* src = arow + pair * 256 + lane * 4;
        __builtin_amdgcn_global_load_lds(
            (const __attribute__((address_space(1))) void*)src,
            (__attribute__((address_space(3))) void*)&ring[wave][pair & 3][0],
            16, 0, 0);
    };

    // prologue DMAs in flight across the xs barrier
    issue(0); issue(1); issue(2);

    // ---- A-fragment: WA1[m][k] in f16; m = n (<16), k = half*8 + e; rows >=16 zero
    union { half2v h2[4]; half8 h8; } au;
    #pragma unroll
    for (int p = 0; p < 4; ++p) {
        float lo = 0.f, hi = 0.f;
        if (n < 16) {
            int k = half * 8 + p * 2;
            lo = WA1[n * 16 + k];
            hi = WA1[n * 16 + k + 1];
        }
        au.h2[p] = cvt2(lo, hi);
    }

    // ---- h0 constants, packed f16: u_k(i) = WA0[k,0]*xi + bA0[k]; w1_k = WA0[k,1]
    half2v u2h[4], w2h[4];
    #pragma unroll
    for (int p = 0; p < 4; ++p) {
        int k0 = half * 8 + p * 2;
        u2h[p] = cvt2(fmaf(WA0[2 * k0],     xi, bA0[k0]),
                      fmaf(WA0[2 * k0 + 2], xi, bA0[k0 + 1]));
        w2h[p] = cvt2(WA0[2 * k0 + 1], WA0[2 * k0 + 3]);
    }

    // ---- layer-2 weights + bA1 as packed-f16 pairs matching D regs (2p, 2p+1)
    half2v wa2h[4], bb[4];
    #pragma unroll
    for (int p = 0; p < 4; ++p) {
        int r  = 2 * p;
        int m0 = (r & 3) + 8 * (r >> 2) + 4 * half;
        wa2h[p] = cvt2(WA2[m0], WA2[m0 + 1]);
        bb[p]   = cvt2(bA1[m0], bA1[m0 + 1]);
    }

    // skip term: only half 0 adds it (each j is held by both halves)
    const float wA1h = half ? 0.f : wA[1];
    const float c0h  = half ? 0.f : (bA2[0] + wA[0] * xi);
    const half2v z2 = { (__fp16)0.f, (__fp16)0.f };
    const f32x16 zc = {};   // zero C-operand -> folds to MFMA inline constant 0

    float acc0 = 0.f, acc1 = 0.f;

    // one 128-j group: 4 MFMA sub-groups, 2-deep MFMA pipeline (proven R10/R11)
    auto body = [&](const f32x4 xv, const f32x4 av) {
        #pragma unroll
        for (int q = 0; q < 4; q += 2) {
            half2v xg0 = cvt2(xv[q], xv[q]);
            union { half2v h2[4]; half8 h8; } b0;
            #pragma unroll
            for (int p = 0; p < 4; ++p)
                b0.h2[p] = __builtin_elementwise_max(w2h[p] * xg0 + u2h[p], z2);
            f32x16 d0 = __builtin_amdgcn_mfma_f32_32x32x16_f16(au.h8, b0.h8, zc, 0, 0, 0);

            half2v xg1 = cvt2(xv[q + 1], xv[q + 1]);
            union { half2v h2[4]; half8 h8; } b1;
            #pragma unroll
            for (int p = 0; p < 4; ++p)
                b1.h2[p] = __builtin_elementwise_max(w2h[p] * xg1 + u2h[p], z2);
            f32x16 d1 = __builtin_amdgcn_mfma_f32_32x32x16_f16(au.h8, b1.h8, zc, 0, 0, 0);

            // epilogue q: packed-f16, D regs 0..7 (rows < 16)
            {
                float pp = fmaf(wA1h, xv[q], c0h);
                #pragma unroll
                for (int p = 0; p < 4; ++p) {
                    half2v t = __builtin_elementwise_max(
                        cvt2(d0[2 * p], d0[2 * p + 1]) + bb[p], z2);
                    pp = __builtin_amdgcn_fdot2(t, wa2h[p], pp, false);
                }
                acc0 = fmaf(av[q], pp, acc0);
            }
            // epilogue q+1
            {
                float pp = fmaf(wA1h, xv[q + 1], c0h);
                #pragma unroll
                for (int p = 0; p < 4; ++p) {
                    half2v t = __builtin_elementwise_max(
                        cvt2(d1[2 * p], d1[2 * p + 1]) + bb[p], z2);
                    pp = __builtin_amdgcn_fdot2(t, wa2h[p], pp, false);
                }
                acc1 = fmaf(av[q + 1], pp, acc1);
            }
        }
    };

    __syncthreads();                 // xs ready (drains prologue DMAs too - harmless)

    const f32x4* xls = (const f32x4*)xs;
    f32x4 xv = xls[n];               // x for group 0

    // STEP: process DMA pair P (groups 2P, 2P+1) from slot P&3.
    // vmcnt counts ONLY our DMAs; WN = outstanding allowed after the wait.
#define STEP(P, WN, DO_ISSUE)                                                \
    {                                                                        \
        if (DO_ISSUE) issue((P) + 3);                                        \
        asm volatile("s_waitcnt vmcnt(" #WN ")" ::: "memory");               \
        __builtin_amdgcn_sched_barrier(0);                                   \
        const f32x4* sp = (const f32x4*)&ring[wave][(P) & 3][0];             \
        f32x4 av0 = sp[n];                                                   \
        f32x4 av1 = sp[32 + n];                                              \
        f32x4 xn0 = xls[(2 * (P) + 1) * 32 + n];                             \
        f32x4 xn1 = ((P) < 15) ? xls[(2 * (P) + 2) * 32 + n] : xn0;          \
        body(xv, av0);                                                       \
        body(xn0, av1);                                                      \
        xv = xn1;                                                            \
    }

    for (int P = 0; P < 13; ++P)
        STEP(P, 3, true);
    STEP(13, 2, false);
    STEP(14, 1, false);
    STEP(15, 0, false);
#undef STEP

    // ---- full-wave reduce; each wave owns its row -> no cross-wave combine
    float acc = acc0 + acc1;
    #pragma unroll
    for (int off = 32; off > 0; off >>= 1)
        acc += __shfl_xor(acc, off);

    if (lane == 0) {
        // node MLP (fp32 exact): x_N = relu(x*Wm0+bm0)@Wm1 + bm1 + wf*x
        float xn = fmaf(wf[0], xi, bm1[0]);
        #pragma unroll
        for (int h = 0; h < 16; ++h)
            xn = fmaf(Wm1[h], fmaxf(fmaf(Wm0[h], xi, bm0[h]), 0.f), xn);
        out[row] = xn + acc;
    }
}

extern "C" void kernel_launch(void* const* d_in, const int* in_sizes, int n_in,
                              void* d_out, int out_size, void* d_ws, size_t ws_size,
                              hipStream_t stream) {
    const float* x   = (const float*)d_in[1];
    const float* A   = (const float*)d_in[2];
    const float* WA0 = (const float*)d_in[3];
    const float* bA0 = (const float*)d_in[4];
    const float* WA1 = (const float*)d_in[5];
    const float* bA1 = (const float*)d_in[6];
    const float* WA2 = (const float*)d_in[7];
    const float* bA2 = (const float*)d_in[8];
    const float* Wm0 = (const float*)d_in[9];
    const float* bm0 = (const float*)d_in[10];
    const float* Wm1 = (const float*)d_in[11];
    const float* bm1 = (const float*)d_in[12];
    const float* wA  = (const float*)d_in[13];
    const float* wf  = (const float*)d_in[14];
    float* out = (float*)d_out;

    odef_kernel<<<NN / 4, 256, 0, stream>>>(x, A, WA0, bA0, WA1, bA1, WA2, bA2,
                                            Wm0, bm0, Wm1, bm1, wA, wf, out);
}